// Round 3
// baseline (1366.281 us; speedup 1.0000x reference)
//
#include <hip/hip_runtime.h>
#include <math.h>

#define Hd 256
#define Wd 256
#define Cd 128
#define BIGV 1.0e9f

static __device__ __forceinline__ float softplus_f(float x) {
    return fmaxf(x, 0.0f) + log1pf(expf(-fabsf(x)));
}

// ---------------------------------------------------------------------------
// Kernel 1: per-pixel fused feature work.
// 16x16 tile/block, 18x18 halo, 32-ch chunks staged as float4 planes in LDS.
// Stencil: 9 ds_read_b128 per 4 channels. MLP weights: LDS float4 broadcast
// reads (conflict-free, 8 per channel).
// ---------------------------------------------------------------------------
#define TILE 16
#define HPX 18
#define PXN 324           // 18*18
#define SP4 325           // float4-plane stride

__global__ __launch_bounds__(256) void k_pixel(
    const float* __restrict__ feat,
    const float* __restrict__ w1, const float* __restrict__ b1,
    const float* __restrict__ w2, const float* __restrict__ b2,
    const int*   __restrict__ endn,
    float* __restrict__ out,
    float* __restrict__ costP,
    float* __restrict__ omgG, float* __restrict__ absG)
{
    __shared__ float4 S4[8 * SP4];     // 41.6 KB
    __shared__ float4 w1L[Cd * 8];     // 16 KB  w1L[ch*8+j4]
    __shared__ float  normL[PXN];      // 1.3 KB
    __shared__ float  endfL[64];

    const int t  = threadIdx.x;
    const int r0 = blockIdx.y * TILE;
    const int c0 = blockIdx.x * TILE;
    const int lr = t >> 4, lc = t & 15;
    const int r = r0 + lr, c = c0 + lc;
    const int px0 = (lr + 1) * HPX + (lc + 1);

    for (int i = t; i < Cd * 8; i += 256)
        w1L[i] = ((const float4*)w1)[i];
    if (t < 64) {
        int ep = endn[0] * Wd + endn[1];
        endfL[t] = feat[ep * Cd + t];          // lf channels 0..63
    }

    float4 hv[8];
#pragma unroll
    for (int j = 0; j < 8; ++j) hv[j] = make_float4(0.f, 0.f, 0.f, 0.f);
    float dotv[8];
#pragma unroll
    for (int j = 0; j < 8; ++j) dotv[j] = 0.0f;
    float gm_acc = 0.0f, var_acc = 0.0f, abs_acc = 0.0f;

    for (int ch0 = 0; ch0 < Cd; ch0 += 32) {
        __syncthreads();                 // previous chunk consumed / w1L ready
        // ---- stage chunk: i -> px = i>>3, g = i&7 (8 float4 per px)
        for (int i = t; i < PXN * 8; i += 256) {
            int px = i >> 3, g = i & 7;
            int pr = px / HPX, pc = px - pr * HPX;
            int gr = r0 - 1 + pr, gc = c0 - 1 + pc;
            float4 v = make_float4(0.f, 0.f, 0.f, 0.f);
            if ((unsigned)gr < Hd && (unsigned)gc < Wd)
                v = *(const float4*)&feat[((gr << 8) + gc) * Cd + ch0 + (g << 2)];
            S4[g * SP4 + px] = v;
        }
        __syncthreads();
        // ---- per-pixel norm partials (all 324 halo pixels)
        for (int px = t; px < PXN; px += 256) {
            float s = 0.0f;
#pragma unroll
            for (int g = 0; g < 8; ++g) {
                float4 qv = S4[g * SP4 + px];
                s = fmaf(qv.x, qv.x, fmaf(qv.y, qv.y, fmaf(qv.z, qv.z, fmaf(qv.w, qv.w, s))));
            }
            normL[px] = (ch0 == 0) ? s : normL[px] + s;
        }
        // ---- fused per-channel compute for own pixel
        const bool is_hf = (ch0 >= 64);
#pragma unroll
        for (int g = 0; g < 8; ++g) {
            const float4* __restrict__ Sg = &S4[g * SP4];
            float4 X  = Sg[px0];
            float4 A0 = Sg[px0 - HPX - 1], A1 = Sg[px0 - HPX], A2 = Sg[px0 - HPX + 1];
            float4 A3 = Sg[px0 - 1],       A4 = Sg[px0 + 1];
            float4 A5 = Sg[px0 + HPX - 1], A6 = Sg[px0 + HPX], A7 = Sg[px0 + HPX + 1];
#pragma unroll
            for (int cc = 0; cc < 4; ++cc) {
                float x  = ((const float*)&X)[cc];
                float n0 = ((const float*)&A0)[cc];
                float n1 = ((const float*)&A1)[cc];
                float n2 = ((const float*)&A2)[cc];
                float n3 = ((const float*)&A3)[cc];
                float n4 = ((const float*)&A4)[cc];
                float n5 = ((const float*)&A5)[cc];
                float n6 = ((const float*)&A6)[cc];
                float n7 = ((const float*)&A7)[cc];

                float gx = (n2 + 2.f * n4 + n7) - (n0 + 2.f * n3 + n5);
                float gy = (n5 + 2.f * n6 + n7) - (n0 + 2.f * n1 + n2);
                gm_acc += sqrtf(fmaf(gx, gx, gy * gy));

                if (is_hf) {
                    float s1 = x + n0 + n1 + n2 + n3 + n4 + n5 + n6 + n7;
                    float s2 = fmaf(x, x, fmaf(n0, n0, fmaf(n1, n1, fmaf(n2, n2,
                               fmaf(n3, n3, fmaf(n4, n4, fmaf(n5, n5,
                               fmaf(n6, n6, n7 * n7))))))));
                    float m = s1 * (1.0f / 9.0f);
                    var_acc += s2 * (1.0f / 9.0f) - m * m;
                } else {
                    float dlf = x - endfL[ch0 + (g << 2) + cc];   // broadcast
                    abs_acc = fmaf(dlf, dlf, abs_acc);
                }

                dotv[0] = fmaf(x, n0, dotv[0]);
                dotv[1] = fmaf(x, n1, dotv[1]);
                dotv[2] = fmaf(x, n2, dotv[2]);
                dotv[3] = fmaf(x, n3, dotv[3]);
                dotv[4] = fmaf(x, n4, dotv[4]);
                dotv[5] = fmaf(x, n5, dotv[5]);
                dotv[6] = fmaf(x, n6, dotv[6]);
                dotv[7] = fmaf(x, n7, dotv[7]);

                const float4* __restrict__ wr4 = &w1L[(ch0 + (g << 2) + cc) << 3];
#pragma unroll
                for (int j4 = 0; j4 < 8; ++j4) {
                    float4 wv = wr4[j4];                          // broadcast b128
                    hv[j4].x = fmaf(x, wv.x, hv[j4].x);
                    hv[j4].y = fmaf(x, wv.y, hv[j4].y);
                    hv[j4].z = fmaf(x, wv.z, hv[j4].z);
                    hv[j4].w = fmaf(x, wv.w, hv[j4].w);
                }
            }
        }
    }
    __syncthreads();   // normL complete before neighbor reads

    // ---- finalize
    const int p = (r << 8) + c;
    float geo  = gm_acc * (1.0f / 128.0f);
    float absp = sqrtf(abs_acc);
    float o = b2[0];
#pragma unroll
    for (int j4 = 0; j4 < 8; ++j4) {
#pragma unroll
        for (int cc = 0; cc < 4; ++cc) {
            int j = (j4 << 2) + cc;
            float hj = fmaxf(((const float*)&hv[j4])[cc] + b1[j], 0.0f);
            o = fmaf(hj, w2[j], o);
        }
    }
    float omg = 1.0f / (1.0f + expf(-o));
    // park geo in out ch0 (overwritten by k_combine) and var in out ch9
    // (overwritten by k_dist); omg/abs in ws planes.
    out[p * 10]     = geo;
    out[p * 10 + 9] = var_acc;
    omgG[p] = omg; absG[p] = absp;

    float np = fmaxf(sqrtf(normL[px0]), 1e-12f);
    const int drr[8] = {-1,-1,-1, 0, 0, 1, 1, 1};
    const int dcc[8] = {-1, 0, 1,-1, 1,-1, 0, 1};
    const int nof[8] = {-HPX-1,-HPX,-HPX+1,-1,1,HPX-1,HPX,HPX+1};
#pragma unroll
    for (int j = 0; j < 8; ++j) {
        int nr = r + drr[j], nc = c + dcc[j];
        float cj;
        if ((unsigned)nr < Hd && (unsigned)nc < Wd) {
            float nn = fmaxf(sqrtf(normL[px0 + nof[j]]), 1e-12f);
            cj = 1.0f - dotv[j] / (np * nn);
        } else {
            cj = BIGV;
        }
        costP[(j << 16) + p] = cj;
        out[p * 10 + 1 + j]  = cj;
    }
}

// ---------------------------------------------------------------------------
// Kernel 2: heuristic combine + flag reset
// ---------------------------------------------------------------------------
__global__ __launch_bounds__(256) void k_combine(
    const float* __restrict__ omgG, const float* __restrict__ absG,
    const float* __restrict__ dlt, const float* __restrict__ gmm,
    const float* __restrict__ bta, const int* __restrict__ endn,
    float* __restrict__ out, int* __restrict__ ready)
{
    if (threadIdx.x == 0) ready[blockIdx.x] = 0;     // flags for k_dist
    int p = blockIdx.x * 256 + threadIdx.x;
    float d = softplus_f(dlt[0]);
    float g = softplus_f(gmm[0]);
    float b = softplus_f(bta[0]);
    float vend = out[(endn[0] * Wd + endn[1]) * 10 + 9];
    float geo  = out[p * 10];
    float var  = out[p * 10 + 9];
    float omg  = omgG[p];
    float heur = d * geo + omg * g * (vend - var)
               + (1.0f - omg) * b * absG[p];
    out[p * 10] = fmaxf(heur, 0.0f);
}

// ---------------------------------------------------------------------------
// Kernel 3: persistent distance map. 256 blocks (one 16x16 core each), 32
// phases x 8 exact Jacobi iterations in LDS. Inter-block halo exchange via
// published cores (double-buffered by phase parity) + device-scope flags.
// Deadlock-safe by capacity: 9.5 KB LDS / ~80 VGPR -> >=4 blocks/CU, grid 256
// <= capacity, so all blocks are resident.
// ---------------------------------------------------------------------------
#define TSTR 35

__global__ __launch_bounds__(256) void k_dist(
    const float* __restrict__ costP, const int* __restrict__ startn,
    float* __restrict__ out, float* __restrict__ coreBuf,
    int* __restrict__ ready)
{
    __shared__ float D[2][34 * TSTR];
    const int t  = threadIdx.x;
    const int tc = t & 31;
    const int q  = t >> 5;
    const int rbase = q << 2;
    const int bx = blockIdx.x, by = blockIdx.y;
    const int b  = (by << 4) + bx;
    const int r0 = by << 4, c0 = bx << 4;       // core origin; tile origin -8

    const int sp = startn[0] * Wd + startn[1];

    for (int i = t; i < 2 * 34 * TSTR; i += 256) (&D[0][0])[i] = BIGV;
    __syncthreads();

    // ---- costs into registers (once) + initial state s0
    float cR[4][8];
#pragma unroll
    for (int i = 0; i < 4; ++i) {
        int tr = rbase + i;
        int gr = r0 - 8 + tr, gc = c0 - 8 + tc;
        bool in = ((unsigned)gr < Hd) && ((unsigned)gc < Wd);
        int p = (gr << 8) + gc;
#pragma unroll
        for (int j = 0; j < 8; ++j)
            cR[i][j] = in ? costP[(j << 16) + p] : BIGV;
        D[0][(tr + 1) * TSTR + tc + 1] = (in && p == sp) ? 0.0f : BIGV;
    }

    const int dR[8] = {-1,-1,-1, 0, 0, 1, 1, 1};
    const int dC[8] = {-1, 0, 1,-1, 1,-1, 0, 1};

    for (int j = 0; j < 32; ++j) {
        if (j > 0) {
            // wait for the 8 neighbors to have published s_j
            if (t < 8) {
                int nbx = bx + dC[t], nby = by + dR[t];
                if ((unsigned)nbx < 16 && (unsigned)nby < 16) {
                    const int nb = (nby << 4) + nbx;
                    while (__hip_atomic_load(&ready[nb], __ATOMIC_ACQUIRE,
                                             __HIP_MEMORY_SCOPE_AGENT) < j)
                        __builtin_amdgcn_s_sleep(1);
                }
            }
            __syncthreads();
            // refill the 8-deep halo frame of D[0] from neighbor cores (s_j)
            const int par = j & 1;
            for (int i = t; i < 768; i += 256) {
                int hr, hc;                         // core-relative coords
                if (i < 256)      { hr = (i >> 5) - 8;        hc = (i & 31) - 8; }
                else if (i < 512) { int k2 = i - 256; hr = 16 + (k2 >> 5); hc = (k2 & 31) - 8; }
                else              { int k2 = i - 512; hr = k2 >> 4;
                                    int m2 = k2 & 15; hc = (m2 < 8) ? m2 - 8 : m2 + 8; }
                int dbx = (hc < 0) ? -1 : (hc >= 16 ? 1 : 0);
                int dby = (hr < 0) ? -1 : (hr >= 16 ? 1 : 0);
                int nbx = bx + dbx, nby = by + dby;
                float v = BIGV;
                if ((unsigned)nbx < 16 && (unsigned)nby < 16) {
                    int nb = (nby << 4) + nbx;
                    v = coreBuf[(((nb << 1) + par) << 8) + ((hr & 15) << 4) + (hc & 15)];
                }
                D[0][(hr + 9) * TSTR + (hc + 9)] = v;
            }
            __syncthreads();
        }
        // ---- 8 exact Jacobi iterations, shrinking active margin
#pragma unroll
        for (int it = 0; it < 8; ++it) {
            const float* __restrict__ Dc = D[it & 1];
            float*       __restrict__ Dn = D[1 - (it & 1)];
            const int m = 7 - it;
            if (rbase + 3 >= 8 - m && rbase <= 23 + m) {
                int idx = rbase * TSTR + tc + 1;
                float a = Dc[idx - 1], bb = Dc[idx], cv = Dc[idx + 1];
                idx += TSTR;
                float d = Dc[idx - 1], e = Dc[idx], f = Dc[idx + 1];
#pragma unroll
                for (int i = 0; i < 4; ++i) {
                    idx += TSTR;
                    float g = Dc[idx - 1], h = Dc[idx], i2 = Dc[idx + 1];
                    float best = e;
                    best = fminf(best, a  + cR[i][0]);
                    best = fminf(best, bb + cR[i][1]);
                    best = fminf(best, cv + cR[i][2]);
                    best = fminf(best, d  + cR[i][3]);
                    best = fminf(best, f  + cR[i][4]);
                    best = fminf(best, g  + cR[i][5]);
                    best = fminf(best, h  + cR[i][6]);
                    best = fminf(best, i2 + cR[i][7]);
                    Dn[idx - TSTR] = best;
                    a = d; bb = e; cv = f;
                    d = g; e = h; f = i2;
                }
            }
            __syncthreads();
        }
        // result (s_{j+1}) is back in D[0]
        if (j < 31) {
            const int par = (j + 1) & 1;
            if (tc >= 8 && tc < 24 && q >= 2 && q < 6) {
#pragma unroll
                for (int i = 0; i < 4; ++i) {
                    int tr = rbase + i;
                    coreBuf[(((b << 1) + par) << 8) + ((tr - 8) << 4) + (tc - 8)]
                        = D[0][(tr + 1) * TSTR + tc + 1];
                }
            }
            __syncthreads();
            __threadfence();
            if (t == 0)
                __hip_atomic_store(&ready[b], j + 1, __ATOMIC_RELEASE,
                                   __HIP_MEMORY_SCOPE_AGENT);
        } else {
            if (tc >= 8 && tc < 24 && q >= 2 && q < 6) {
#pragma unroll
                for (int i = 0; i < 4; ++i) {
                    int tr = rbase + i;
                    int gr = r0 - 8 + tr, gc = c0 - 8 + tc;
                    float v = D[0][(tr + 1) * TSTR + tc + 1];
                    out[((gr << 8) + gc) * 10 + 9] = fminf(v, BIGV);
                }
            }
        }
    }
}

// ---------------------------------------------------------------------------
extern "C" void kernel_launch(void* const* d_in, const int* in_sizes, int n_in,
                              void* d_out, int out_size, void* d_ws, size_t ws_size,
                              hipStream_t stream)
{
    const float* feat  = (const float*)d_in[0];
    const float* dlt   = (const float*)d_in[1];
    const float* gmm   = (const float*)d_in[2];
    const float* bta   = (const float*)d_in[3];
    const float* w1    = (const float*)d_in[4];
    const float* b1    = (const float*)d_in[5];
    const float* w2    = (const float*)d_in[6];
    const float* b2    = (const float*)d_in[7];
    const int*   startn= (const int*)d_in[8];
    const int*   endn  = (const int*)d_in[9];
    float* out = (float*)d_out;
    float* ws  = (float*)d_ws;

    float* costP   = ws;                        // 8 planes
    float* omgG    = ws + 8 * 65536;            // 1 plane
    float* absG    = ws + 9 * 65536;            // 1 plane
    float* coreBuf = ws + 10 * 65536;           // 2 planes (256 blk x 2 x 256)
    int*   ready   = (int*)(ws + 12 * 65536);   // 1 KB

    dim3 g16(16, 16);
    k_pixel<<<g16, 256, 0, stream>>>(feat, w1, b1, w2, b2, endn,
                                     out, costP, omgG, absG);
    k_combine<<<256, 256, 0, stream>>>(omgG, absG, dlt, gmm, bta, endn,
                                       out, ready);
    k_dist<<<g16, 256, 0, stream>>>(costP, startn, out, coreBuf, ready);
}

// Round 4
// 300.598 us; speedup vs baseline: 4.5452x; 4.5452x over previous
//
#include <hip/hip_runtime.h>
#include <math.h>

#define Hd 256
#define Wd 256
#define Cd 128
#define BIGV 1.0e9f

static __device__ __forceinline__ float softplus_f(float x) {
    return fmaxf(x, 0.0f) + log1pf(expf(-fabsf(x)));
}

// ---------------------------------------------------------------------------
// Kernel 1: per-pixel fused feature work (round-1 proven version, ~66 us).
// 16x16 pixel tile per block (256 threads, 1 px/thread), 18x18 halo staging,
// channel-chunked (32 ch) in LDS with planar [ch][px] layout (stride 325).
// ---------------------------------------------------------------------------
#define TILE 16
#define HPX 18
#define PXN 324          // 18*18
#define SP  325          // padded plane stride (325 % 32 != 0)
#define CHUNK 32

__global__ __launch_bounds__(256) void k_pixel(
    const float* __restrict__ feat,
    const float* __restrict__ w1, const float* __restrict__ b1,
    const float* __restrict__ w2, const float* __restrict__ b2,
    const int*   __restrict__ endn,
    float* __restrict__ out,
    float* __restrict__ costP,
    float* __restrict__ geoG, float* __restrict__ varG,
    float* __restrict__ omgG, float* __restrict__ absG)
{
    __shared__ float stage[CHUNK * SP];
    __shared__ float normL[PXN];
    __shared__ float w1L[Cd * 32];
    __shared__ float endfL[64];

    const int t  = threadIdx.x;
    const int r0 = blockIdx.y * TILE;
    const int c0 = blockIdx.x * TILE;

    for (int i = t; i < Cd * 32; i += 256) w1L[i] = w1[i];
    if (t < 64) {
        int ep = endn[0] * Wd + endn[1];
        endfL[t] = feat[ep * Cd + t];
    }

    const int lr = t >> 4, lc = t & 15;
    const int r = r0 + lr, c = c0 + lc;
    const int px0 = (lr + 1) * HPX + (lc + 1);

    float hA[32];
#pragma unroll
    for (int j = 0; j < 32; ++j) hA[j] = 0.0f;
    float dotv[8];
#pragma unroll
    for (int j = 0; j < 8; ++j) dotv[j] = 0.0f;
    float gm_acc = 0.0f, var_acc = 0.0f, abs_acc = 0.0f;

    for (int ch0 = 0; ch0 < Cd; ch0 += CHUNK) {
        __syncthreads();   // protect stage (and w1L on first pass)
        for (int i = t; i < PXN * 8; i += 256) {
            int px = i >> 3, f4 = i & 7;
            int pr = px / HPX;
            int pc = px - pr * HPX;
            int gr = r0 - 1 + pr, gc = c0 - 1 + pc;
            float4 v = make_float4(0.f, 0.f, 0.f, 0.f);
            if ((unsigned)gr < Hd && (unsigned)gc < Wd) {
                v = *reinterpret_cast<const float4*>(
                        &feat[(((gr << 8) + gc) * Cd) + ch0 + (f4 << 2)]);
            }
            int chb = f4 << 2;
            stage[(chb + 0) * SP + px] = v.x;
            stage[(chb + 1) * SP + px] = v.y;
            stage[(chb + 2) * SP + px] = v.z;
            stage[(chb + 3) * SP + px] = v.w;
        }
        __syncthreads();
        for (int px = t; px < PXN; px += 256) {
            float s = 0.0f;
#pragma unroll
            for (int ch = 0; ch < CHUNK; ++ch) {
                float v = stage[ch * SP + px];
                s = fmaf(v, v, s);
            }
            if (ch0 == 0) normL[px] = s; else normL[px] += s;
        }
        const bool is_hf = (ch0 >= 64);
        for (int ch = 0; ch < CHUNK; ++ch) {
            const float* pl = stage + ch * SP + px0;
            float x  = pl[0];
            float n0 = pl[-HPX - 1], n1 = pl[-HPX], n2 = pl[-HPX + 1];
            float n3 = pl[-1],                      n4 = pl[1];
            float n5 = pl[HPX - 1],  n6 = pl[HPX],  n7 = pl[HPX + 1];

            float gx = (n2 + 2.f * n4 + n7) - (n0 + 2.f * n3 + n5);
            float gy = (n5 + 2.f * n6 + n7) - (n0 + 2.f * n1 + n2);
            gm_acc += sqrtf(gx * gx + gy * gy);

            if (is_hf) {
                float s1 = x + n0 + n1 + n2 + n3 + n4 + n5 + n6 + n7;
                float s2 = x*x + n0*n0 + n1*n1 + n2*n2 + n3*n3 + n4*n4
                         + n5*n5 + n6*n6 + n7*n7;
                float m = s1 * (1.0f / 9.0f);
                var_acc += s2 * (1.0f / 9.0f) - m * m;
            } else {
                float dlf = x - endfL[ch0 + ch];
                abs_acc = fmaf(dlf, dlf, abs_acc);
            }

            dotv[0] = fmaf(x, n0, dotv[0]);
            dotv[1] = fmaf(x, n1, dotv[1]);
            dotv[2] = fmaf(x, n2, dotv[2]);
            dotv[3] = fmaf(x, n3, dotv[3]);
            dotv[4] = fmaf(x, n4, dotv[4]);
            dotv[5] = fmaf(x, n5, dotv[5]);
            dotv[6] = fmaf(x, n6, dotv[6]);
            dotv[7] = fmaf(x, n7, dotv[7]);

            const float* wrow = &w1L[(ch0 + ch) << 5];
#pragma unroll
            for (int j = 0; j < 32; ++j) hA[j] = fmaf(x, wrow[j], hA[j]);
        }
    }
    __syncthreads();   // normL complete before neighbor reads

    const int p = (r << 8) + c;
    float geo  = gm_acc * (1.0f / 128.0f);
    float absp = sqrtf(abs_acc);
    float o = b2[0];
#pragma unroll
    for (int j = 0; j < 32; ++j) {
        float hj = fmaxf(hA[j] + b1[j], 0.0f);
        o = fmaf(hj, w2[j], o);
    }
    float omg = 1.0f / (1.0f + expf(-o));
    geoG[p] = geo; varG[p] = var_acc; omgG[p] = omg; absG[p] = absp;

    float np = fmaxf(sqrtf(normL[px0]), 1e-12f);
    const int drr[8] = {-1,-1,-1, 0, 0, 1, 1, 1};
    const int dcc[8] = {-1, 0, 1,-1, 1,-1, 0, 1};
    const int nof[8] = {-HPX-1,-HPX,-HPX+1,-1,1,HPX-1,HPX,HPX+1};
#pragma unroll
    for (int j = 0; j < 8; ++j) {
        int nr = r + drr[j], nc = c + dcc[j];
        float cj;
        if ((unsigned)nr < Hd && (unsigned)nc < Wd) {
            float nn = fmaxf(sqrtf(normL[px0 + nof[j]]), 1e-12f);
            cj = 1.0f - dotv[j] / (np * nn);
        } else {
            cj = BIGV;
        }
        costP[(j << 16) + p] = cj;
        out[p * 10 + 1 + j]  = cj;
    }
}

// ---------------------------------------------------------------------------
// Kernel 2: heuristic combine + flag reset
// ---------------------------------------------------------------------------
__global__ __launch_bounds__(256) void k_combine(
    const float* __restrict__ geoG, const float* __restrict__ varG,
    const float* __restrict__ omgG, const float* __restrict__ absG,
    const float* __restrict__ dlt, const float* __restrict__ gmm,
    const float* __restrict__ bta, const int* __restrict__ endn,
    float* __restrict__ out, int* __restrict__ ready)
{
    if (threadIdx.x == 0) ready[blockIdx.x] = 0;   // flags for k_dist
    int p = blockIdx.x * 256 + threadIdx.x;
    float d = softplus_f(dlt[0]);
    float g = softplus_f(gmm[0]);
    float b = softplus_f(bta[0]);
    float vend = varG[endn[0] * Wd + endn[1]];
    float omg  = omgG[p];
    float heur = d * geoG[p] + omg * g * (vend - varG[p])
               + (1.0f - omg) * b * absG[p];
    out[p * 10] = fmaxf(heur, 0.0f);
}

// ---------------------------------------------------------------------------
// Kernel 3: persistent distance map. 256 blocks (one 16x16 core each), 32
// phases x 8 exact Jacobi iterations in LDS. Inter-block halo exchange via
// published cores (double-buffered by phase parity) + flags.
// ALL cross-block traffic uses RELAXED agent-scope atomics (MALL-coherent,
// bypass non-coherent per-XCD L2, NO buffer_inv/wbl2 side effects).
// Ordering: __syncthreads() drains vmcnt(0) before s_barrier, so
// core-stores -> barrier -> flag-store is ordered without fences.
// Defensive: every 32nd poll uses acquire (progress even if relaxed stales).
// ---------------------------------------------------------------------------
#define TSTR 35

__global__ __launch_bounds__(256) void k_dist(
    const float* __restrict__ costP, const int* __restrict__ startn,
    float* __restrict__ out, float* coreBuf, int* ready)
{
    __shared__ float D[2][34 * TSTR];
    const int t  = threadIdx.x;
    const int tc = t & 31;
    const int q  = t >> 5;
    const int rbase = q << 2;
    const int bx = blockIdx.x, by = blockIdx.y;
    const int b  = (by << 4) + bx;
    const int r0 = by << 4, c0 = bx << 4;       // core origin; tile origin -8

    const int sp = startn[0] * Wd + startn[1];

    for (int i = t; i < 2 * 34 * TSTR; i += 256) (&D[0][0])[i] = BIGV;
    __syncthreads();

    // ---- costs into registers (once) + initial state s0
    float cR[4][8];
#pragma unroll
    for (int i = 0; i < 4; ++i) {
        int tr = rbase + i;
        int gr = r0 - 8 + tr, gc = c0 - 8 + tc;
        bool in = ((unsigned)gr < Hd) && ((unsigned)gc < Wd);
        int p = (gr << 8) + gc;
#pragma unroll
        for (int j = 0; j < 8; ++j)
            cR[i][j] = in ? costP[(j << 16) + p] : BIGV;
        D[0][(tr + 1) * TSTR + tc + 1] = (in && p == sp) ? 0.0f : BIGV;
    }

    const int dR[8] = {-1,-1,-1, 0, 0, 1, 1, 1};
    const int dC[8] = {-1, 0, 1,-1, 1,-1, 0, 1};

    for (int j = 0; j < 32; ++j) {
        if (j > 0) {
            // wait for the 8 neighbors to have published s_j (relaxed polls)
            if (t < 8) {
                int nbx = bx + dC[t], nby = by + dR[t];
                if ((unsigned)nbx < 16 && (unsigned)nby < 16) {
                    const int nb = (nby << 4) + nbx;
                    int polls = 0;
                    for (;;) {
                        int v = (((++polls) & 31) == 0)
                            ? __hip_atomic_load(&ready[nb], __ATOMIC_ACQUIRE,
                                                __HIP_MEMORY_SCOPE_AGENT)
                            : __hip_atomic_load(&ready[nb], __ATOMIC_RELAXED,
                                                __HIP_MEMORY_SCOPE_AGENT);
                        if (v >= j) break;
                        __builtin_amdgcn_s_sleep(1);
                    }
                }
            }
            __syncthreads();
            // refill the 8-deep halo frame of D[0] from neighbor cores (s_j)
            const int par = j & 1;
            for (int i = t; i < 768; i += 256) {
                int hr, hc;                         // core-relative coords
                if (i < 256)      { hr = (i >> 5) - 8;        hc = (i & 31) - 8; }
                else if (i < 512) { int k2 = i - 256; hr = 16 + (k2 >> 5); hc = (k2 & 31) - 8; }
                else              { int k2 = i - 512; hr = k2 >> 4;
                                    int m2 = k2 & 15; hc = (m2 < 8) ? m2 - 8 : m2 + 8; }
                int dbx = (hc < 0) ? -1 : (hc >= 16 ? 1 : 0);
                int dby = (hr < 0) ? -1 : (hr >= 16 ? 1 : 0);
                int nbx = bx + dbx, nby = by + dby;
                float v = BIGV;
                if ((unsigned)nbx < 16 && (unsigned)nby < 16) {
                    int nb = (nby << 4) + nbx;
                    v = __hip_atomic_load(
                        &coreBuf[(((nb << 1) + par) << 8) + ((hr & 15) << 4) + (hc & 15)],
                        __ATOMIC_RELAXED, __HIP_MEMORY_SCOPE_AGENT);
                }
                D[0][(hr + 9) * TSTR + (hc + 9)] = v;
            }
            __syncthreads();
        }
        // ---- 8 exact Jacobi iterations, shrinking active margin
#pragma unroll
        for (int it = 0; it < 8; ++it) {
            const float* __restrict__ Dc = D[it & 1];
            float*       __restrict__ Dn = D[1 - (it & 1)];
            const int m = 7 - it;
            if (rbase + 3 >= 8 - m && rbase <= 23 + m) {
                int idx = rbase * TSTR + tc + 1;
                float a = Dc[idx - 1], bb = Dc[idx], cv = Dc[idx + 1];
                idx += TSTR;
                float d = Dc[idx - 1], e = Dc[idx], f = Dc[idx + 1];
#pragma unroll
                for (int i = 0; i < 4; ++i) {
                    idx += TSTR;
                    float g = Dc[idx - 1], h = Dc[idx], i2 = Dc[idx + 1];
                    float best = e;
                    best = fminf(best, a  + cR[i][0]);
                    best = fminf(best, bb + cR[i][1]);
                    best = fminf(best, cv + cR[i][2]);
                    best = fminf(best, d  + cR[i][3]);
                    best = fminf(best, f  + cR[i][4]);
                    best = fminf(best, g  + cR[i][5]);
                    best = fminf(best, h  + cR[i][6]);
                    best = fminf(best, i2 + cR[i][7]);
                    Dn[idx - TSTR] = best;
                    a = d; bb = e; cv = f;
                    d = g; e = h; f = i2;
                }
            }
            __syncthreads();
        }
        // result (s_{j+1}) is back in D[0]
        if (j < 31) {
            const int par = (j + 1) & 1;
            if (tc >= 8 && tc < 24 && q >= 2 && q < 6) {
#pragma unroll
                for (int i = 0; i < 4; ++i) {
                    int tr = rbase + i;
                    __hip_atomic_store(
                        &coreBuf[(((b << 1) + par) << 8) + ((tr - 8) << 4) + (tc - 8)],
                        D[0][(tr + 1) * TSTR + tc + 1],
                        __ATOMIC_RELAXED, __HIP_MEMORY_SCOPE_AGENT);
                }
            }
            __syncthreads();   // drains vmcnt(0): stores complete before flag
            if (t == 0)
                __hip_atomic_store(&ready[b], j + 1, __ATOMIC_RELAXED,
                                   __HIP_MEMORY_SCOPE_AGENT);
        } else {
            if (tc >= 8 && tc < 24 && q >= 2 && q < 6) {
#pragma unroll
                for (int i = 0; i < 4; ++i) {
                    int tr = rbase + i;
                    int gr = r0 - 8 + tr, gc = c0 - 8 + tc;
                    float v = D[0][(tr + 1) * TSTR + tc + 1];
                    out[((gr << 8) + gc) * 10 + 9] = fminf(v, BIGV);
                }
            }
        }
    }
}

// ---------------------------------------------------------------------------
extern "C" void kernel_launch(void* const* d_in, const int* in_sizes, int n_in,
                              void* d_out, int out_size, void* d_ws, size_t ws_size,
                              hipStream_t stream)
{
    const float* feat  = (const float*)d_in[0];
    const float* dlt   = (const float*)d_in[1];
    const float* gmm   = (const float*)d_in[2];
    const float* bta   = (const float*)d_in[3];
    const float* w1    = (const float*)d_in[4];
    const float* b1    = (const float*)d_in[5];
    const float* w2    = (const float*)d_in[6];
    const float* b2    = (const float*)d_in[7];
    const int*   startn= (const int*)d_in[8];
    const int*   endn  = (const int*)d_in[9];
    float* out = (float*)d_out;
    float* ws  = (float*)d_ws;

    float* costP   = ws;                        // 8 planes
    float* geoG    = ws + 8 * 65536;
    float* varG    = ws + 9 * 65536;
    float* omgG    = ws + 10 * 65536;
    float* absG    = ws + 11 * 65536;
    float* coreBuf = ws + 12 * 65536;           // 2 planes (256 blk x 2 x 256)
    int*   ready   = (int*)(ws + 14 * 65536);   // 1 KB

    dim3 g16(16, 16);
    k_pixel<<<g16, 256, 0, stream>>>(feat, w1, b1, w2, b2, endn,
                                     out, costP, geoG, varG, omgG, absG);
    k_combine<<<256, 256, 0, stream>>>(geoG, varG, omgG, absG,
                                       dlt, gmm, bta, endn, out, ready);
    k_dist<<<g16, 256, 0, stream>>>(costP, startn, out, coreBuf, ready);
}

// Round 5
// 267.292 us; speedup vs baseline: 5.1116x; 1.1246x over previous
//
#include <hip/hip_runtime.h>
#include <math.h>

#define Hd 256
#define Wd 256
#define Cd 128
#define BIGV 1.0e9f

static __device__ __forceinline__ float softplus_f(float x) {
    return fmaxf(x, 0.0f) + log1pf(expf(-fabsf(x)));
}

// ---------------------------------------------------------------------------
// Kernel 1: per-pixel fused feature work (round-1 structure; weights b128).
// 16x16 pixel tile per block, 18x18 halo staging, 32-ch chunks in LDS planes.
// Per-channel LDS issue: 9 ds_read_b32 stencil + 8 ds_read_b128 weights.
// ---------------------------------------------------------------------------
#define TILE 16
#define HPX 18
#define PXN 324          // 18*18
#define SP  325          // padded plane stride (325 % 32 != 0)
#define CHUNK 32

__global__ __launch_bounds__(256) void k_pixel(
    const float* __restrict__ feat,
    const float* __restrict__ w1, const float* __restrict__ b1,
    const float* __restrict__ w2, const float* __restrict__ b2,
    const int*   __restrict__ endn,
    float* __restrict__ out,
    float* __restrict__ costP,
    float* __restrict__ geoG, float* __restrict__ varG,
    float* __restrict__ omgG, float* __restrict__ absG)
{
    __shared__ float  stage[CHUNK * SP];   // 41.6 KB
    __shared__ float  normL[PXN];
    __shared__ float4 w1L[Cd * 8];         // 16 KB  w1L[ch*8 + j4]
    __shared__ float  endfL[64];

    const int t  = threadIdx.x;
    const int r0 = blockIdx.y * TILE;
    const int c0 = blockIdx.x * TILE;

    for (int i = t; i < Cd * 8; i += 256) w1L[i] = ((const float4*)w1)[i];
    if (t < 64) {
        int ep = endn[0] * Wd + endn[1];
        endfL[t] = feat[ep * Cd + t];
    }

    const int lr = t >> 4, lc = t & 15;
    const int r = r0 + lr, c = c0 + lc;
    const int px0 = (lr + 1) * HPX + (lc + 1);

    float4 hv[8];
#pragma unroll
    for (int j = 0; j < 8; ++j) hv[j] = make_float4(0.f, 0.f, 0.f, 0.f);
    float dotv[8];
#pragma unroll
    for (int j = 0; j < 8; ++j) dotv[j] = 0.0f;
    float gm_acc = 0.0f, var_acc = 0.0f, abs_acc = 0.0f;

    for (int ch0 = 0; ch0 < Cd; ch0 += CHUNK) {
        __syncthreads();   // protect stage (and w1L on first pass)
        for (int i = t; i < PXN * 8; i += 256) {
            int px = i >> 3, f4 = i & 7;
            int pr = px / HPX;
            int pc = px - pr * HPX;
            int gr = r0 - 1 + pr, gc = c0 - 1 + pc;
            float4 v = make_float4(0.f, 0.f, 0.f, 0.f);
            if ((unsigned)gr < Hd && (unsigned)gc < Wd) {
                v = *reinterpret_cast<const float4*>(
                        &feat[(((gr << 8) + gc) * Cd) + ch0 + (f4 << 2)]);
            }
            int chb = f4 << 2;
            stage[(chb + 0) * SP + px] = v.x;
            stage[(chb + 1) * SP + px] = v.y;
            stage[(chb + 2) * SP + px] = v.z;
            stage[(chb + 3) * SP + px] = v.w;
        }
        __syncthreads();
        for (int px = t; px < PXN; px += 256) {
            float s = 0.0f;
#pragma unroll
            for (int ch = 0; ch < CHUNK; ++ch) {
                float v = stage[ch * SP + px];
                s = fmaf(v, v, s);
            }
            if (ch0 == 0) normL[px] = s; else normL[px] += s;
        }
        const bool is_hf = (ch0 >= 64);
        for (int ch = 0; ch < CHUNK; ++ch) {
            const float* pl = stage + ch * SP + px0;
            float x  = pl[0];
            float n0 = pl[-HPX - 1], n1 = pl[-HPX], n2 = pl[-HPX + 1];
            float n3 = pl[-1],                      n4 = pl[1];
            float n5 = pl[HPX - 1],  n6 = pl[HPX],  n7 = pl[HPX + 1];

            float gx = (n2 + 2.f * n4 + n7) - (n0 + 2.f * n3 + n5);
            float gy = (n5 + 2.f * n6 + n7) - (n0 + 2.f * n1 + n2);
            gm_acc += sqrtf(gx * gx + gy * gy);

            if (is_hf) {
                float s1 = x + n0 + n1 + n2 + n3 + n4 + n5 + n6 + n7;
                float s2 = x*x + n0*n0 + n1*n1 + n2*n2 + n3*n3 + n4*n4
                         + n5*n5 + n6*n6 + n7*n7;
                float m = s1 * (1.0f / 9.0f);
                var_acc += s2 * (1.0f / 9.0f) - m * m;
            } else {
                float dlf = x - endfL[ch0 + ch];
                abs_acc = fmaf(dlf, dlf, abs_acc);
            }

            dotv[0] = fmaf(x, n0, dotv[0]);
            dotv[1] = fmaf(x, n1, dotv[1]);
            dotv[2] = fmaf(x, n2, dotv[2]);
            dotv[3] = fmaf(x, n3, dotv[3]);
            dotv[4] = fmaf(x, n4, dotv[4]);
            dotv[5] = fmaf(x, n5, dotv[5]);
            dotv[6] = fmaf(x, n6, dotv[6]);
            dotv[7] = fmaf(x, n7, dotv[7]);

            const float4* __restrict__ wr4 = &w1L[(ch0 + ch) << 3];
#pragma unroll
            for (int j4 = 0; j4 < 8; ++j4) {
                float4 wv = wr4[j4];                  // broadcast ds_read_b128
                hv[j4].x = fmaf(x, wv.x, hv[j4].x);
                hv[j4].y = fmaf(x, wv.y, hv[j4].y);
                hv[j4].z = fmaf(x, wv.z, hv[j4].z);
                hv[j4].w = fmaf(x, wv.w, hv[j4].w);
            }
        }
    }
    __syncthreads();   // normL complete before neighbor reads

    const int p = (r << 8) + c;
    float geo  = gm_acc * (1.0f / 128.0f);
    float absp = sqrtf(abs_acc);
    float o = b2[0];
#pragma unroll
    for (int j4 = 0; j4 < 8; ++j4) {
#pragma unroll
        for (int cc = 0; cc < 4; ++cc) {
            int j = (j4 << 2) + cc;
            float hj = fmaxf(((const float*)&hv[j4])[cc] + b1[j], 0.0f);
            o = fmaf(hj, w2[j], o);
        }
    }
    float omg = 1.0f / (1.0f + expf(-o));
    geoG[p] = geo; varG[p] = var_acc; omgG[p] = omg; absG[p] = absp;

    float np = fmaxf(sqrtf(normL[px0]), 1e-12f);
    const int drr[8] = {-1,-1,-1, 0, 0, 1, 1, 1};
    const int dcc[8] = {-1, 0, 1,-1, 1,-1, 0, 1};
    const int nof[8] = {-HPX-1,-HPX,-HPX+1,-1,1,HPX-1,HPX,HPX+1};
#pragma unroll
    for (int j = 0; j < 8; ++j) {
        int nr = r + drr[j], nc = c + dcc[j];
        float cj;
        if ((unsigned)nr < Hd && (unsigned)nc < Wd) {
            float nn = fmaxf(sqrtf(normL[px0 + nof[j]]), 1e-12f);
            cj = 1.0f - dotv[j] / (np * nn);
        } else {
            cj = BIGV;
        }
        costP[(j << 16) + p] = cj;
        out[p * 10 + 1 + j]  = cj;
    }
}

// ---------------------------------------------------------------------------
// Kernel 2: heuristic combine
// ---------------------------------------------------------------------------
__global__ __launch_bounds__(256) void k_combine(
    const float* __restrict__ geoG, const float* __restrict__ varG,
    const float* __restrict__ omgG, const float* __restrict__ absG,
    const float* __restrict__ dlt, const float* __restrict__ gmm,
    const float* __restrict__ bta, const int* __restrict__ endn,
    float* __restrict__ out)
{
    int p = blockIdx.x * 256 + threadIdx.x;
    float d = softplus_f(dlt[0]);
    float g = softplus_f(gmm[0]);
    float b = softplus_f(bta[0]);
    float vend = varG[endn[0] * Wd + endn[1]];
    float omg  = omgG[p];
    float heur = d * geoG[p] + omg * g * (vend - varG[p])
               + (1.0f - omg) * b * absG[p];
    out[p * 10] = fmaxf(heur, 0.0f);
}

// ---------------------------------------------------------------------------
// Kernel 3: persistent distance map, TAGGED-DATA sync (no flags).
// Each published halo cell is a 64-bit (tag<<32 | float bits) relaxed
// agent-scope atomic store; readers poll the data itself for tag == phase.
// Parity double-buffer keeps the 2-phase-deep overwrite-safety argument.
// Harness poisons ws to 0xAA, so stale tags (0xAAAAAAAA) never match j.
// Deadlock-safe by capacity (9.5 KB LDS, grid 256 = 1 block/CU resident);
// insurance acquire every 256 poll retries.
// ---------------------------------------------------------------------------
#define TSTR 35

__global__ __launch_bounds__(256) void k_dist(
    const float* __restrict__ costP, const int* __restrict__ startn,
    float* __restrict__ out, unsigned long long* coreBuf)
{
    __shared__ float D[2][34 * TSTR];
    const int t  = threadIdx.x;
    const int tc = t & 31;
    const int q  = t >> 5;
    const int rbase = q << 2;
    const int bx = blockIdx.x, by = blockIdx.y;
    const int b  = (by << 4) + bx;
    const int r0 = by << 4, c0 = bx << 4;       // core origin; tile origin -8

    const int sp = startn[0] * Wd + startn[1];

    for (int i = t; i < 2 * 34 * TSTR; i += 256) (&D[0][0])[i] = BIGV;
    __syncthreads();

    // ---- costs into registers (once) + initial state s0
    float cR[4][8];
#pragma unroll
    for (int i = 0; i < 4; ++i) {
        int tr = rbase + i;
        int gr = r0 - 8 + tr, gc = c0 - 8 + tc;
        bool in = ((unsigned)gr < Hd) && ((unsigned)gc < Wd);
        int p = (gr << 8) + gc;
#pragma unroll
        for (int j = 0; j < 8; ++j)
            cR[i][j] = in ? costP[(j << 16) + p] : BIGV;
        D[0][(tr + 1) * TSTR + tc + 1] = (in && p == sp) ? 0.0f : BIGV;
    }
    __syncthreads();

    for (int j = 0; j < 32; ++j) {
        if (j > 0) {
            // refill the 8-deep halo frame from neighbor cores: poll the
            // tagged data directly (tag must equal j; parity slot j&1)
            const int par = j & 1;
            for (int i = t; i < 768; i += 256) {
                int hr, hc;                         // core-relative coords
                if (i < 256)      { hr = (i >> 5) - 8;        hc = (i & 31) - 8; }
                else if (i < 512) { int k2 = i - 256; hr = 16 + (k2 >> 5); hc = (k2 & 31) - 8; }
                else              { int k2 = i - 512; hr = k2 >> 4;
                                    int m2 = k2 & 15; hc = (m2 < 8) ? m2 - 8 : m2 + 8; }
                int dbx = (hc < 0) ? -1 : (hc >= 16 ? 1 : 0);
                int dby = (hr < 0) ? -1 : (hr >= 16 ? 1 : 0);
                int nbx = bx + dbx, nby = by + dby;
                float v = BIGV;
                if ((unsigned)nbx < 16 && (unsigned)nby < 16) {
                    int nb = (nby << 4) + nbx;
                    unsigned long long* ptr =
                        &coreBuf[(((nb << 1) + par) << 8) + ((hr & 15) << 4) + (hc & 15)];
                    int retries = 0;
                    unsigned long long u;
                    for (;;) {
                        u = (((++retries) & 255) == 0)
                            ? __hip_atomic_load(ptr, __ATOMIC_ACQUIRE,
                                                __HIP_MEMORY_SCOPE_AGENT)
                            : __hip_atomic_load(ptr, __ATOMIC_RELAXED,
                                                __HIP_MEMORY_SCOPE_AGENT);
                        if ((int)(u >> 32) == j) break;
                        __builtin_amdgcn_s_sleep(1);
                    }
                    unsigned int lo = (unsigned int)u;
                    v = __uint_as_float(lo);
                }
                D[0][(hr + 9) * TSTR + (hc + 9)] = v;
            }
            __syncthreads();
        }
        // ---- 8 exact Jacobi iterations, shrinking active margin
#pragma unroll
        for (int it = 0; it < 8; ++it) {
            const float* __restrict__ Dc = D[it & 1];
            float*       __restrict__ Dn = D[1 - (it & 1)];
            const int m = 7 - it;
            if (rbase + 3 >= 8 - m && rbase <= 23 + m) {
                int idx = rbase * TSTR + tc + 1;
                float a = Dc[idx - 1], bb = Dc[idx], cv = Dc[idx + 1];
                idx += TSTR;
                float d = Dc[idx - 1], e = Dc[idx], f = Dc[idx + 1];
#pragma unroll
                for (int i = 0; i < 4; ++i) {
                    idx += TSTR;
                    float g = Dc[idx - 1], h = Dc[idx], i2 = Dc[idx + 1];
                    float best = e;
                    best = fminf(best, a  + cR[i][0]);
                    best = fminf(best, bb + cR[i][1]);
                    best = fminf(best, cv + cR[i][2]);
                    best = fminf(best, d  + cR[i][3]);
                    best = fminf(best, f  + cR[i][4]);
                    best = fminf(best, g  + cR[i][5]);
                    best = fminf(best, h  + cR[i][6]);
                    best = fminf(best, i2 + cR[i][7]);
                    Dn[idx - TSTR] = best;
                    a = d; bb = e; cv = f;
                    d = g; e = h; f = i2;
                }
            }
            __syncthreads();
        }
        // result (s_{j+1}) is back in D[0]; publish tagged core (fire-and-forget)
        if (j < 31) {
            const int par = (j + 1) & 1;
            if (tc >= 8 && tc < 24 && q >= 2 && q < 6) {
#pragma unroll
                for (int i = 0; i < 4; ++i) {
                    int tr = rbase + i;
                    float v = D[0][(tr + 1) * TSTR + tc + 1];
                    unsigned long long u =
                        (((unsigned long long)(unsigned int)(j + 1)) << 32)
                        | (unsigned long long)__float_as_uint(v);
                    __hip_atomic_store(
                        &coreBuf[(((b << 1) + par) << 8) + ((tr - 8) << 4) + (tc - 8)],
                        u, __ATOMIC_RELAXED, __HIP_MEMORY_SCOPE_AGENT);
                }
            }
            // no barrier/flag needed: readers poll the tagged data itself
        } else {
            if (tc >= 8 && tc < 24 && q >= 2 && q < 6) {
#pragma unroll
                for (int i = 0; i < 4; ++i) {
                    int tr = rbase + i;
                    int gr = r0 - 8 + tr, gc = c0 - 8 + tc;
                    float v = D[0][(tr + 1) * TSTR + tc + 1];
                    out[((gr << 8) + gc) * 10 + 9] = fminf(v, BIGV);
                }
            }
        }
    }
}

// ---------------------------------------------------------------------------
extern "C" void kernel_launch(void* const* d_in, const int* in_sizes, int n_in,
                              void* d_out, int out_size, void* d_ws, size_t ws_size,
                              hipStream_t stream)
{
    const float* feat  = (const float*)d_in[0];
    const float* dlt   = (const float*)d_in[1];
    const float* gmm   = (const float*)d_in[2];
    const float* bta   = (const float*)d_in[3];
    const float* w1    = (const float*)d_in[4];
    const float* b1    = (const float*)d_in[5];
    const float* w2    = (const float*)d_in[6];
    const float* b2    = (const float*)d_in[7];
    const int*   startn= (const int*)d_in[8];
    const int*   endn  = (const int*)d_in[9];
    float* out = (float*)d_out;
    float* ws  = (float*)d_ws;

    float* costP = ws;                          // 8 planes of 65536 floats
    float* geoG  = ws + 8 * 65536;
    float* varG  = ws + 9 * 65536;
    float* omgG  = ws + 10 * 65536;
    float* absG  = ws + 11 * 65536;
    unsigned long long* coreBuf =
        (unsigned long long*)(ws + 12 * 65536);  // 256 blk x 2 par x 256 x 8B = 1 MB

    dim3 g16(16, 16);
    k_pixel<<<g16, 256, 0, stream>>>(feat, w1, b1, w2, b2, endn,
                                     out, costP, geoG, varG, omgG, absG);
    k_combine<<<256, 256, 0, stream>>>(geoG, varG, omgG, absG,
                                       dlt, gmm, bta, endn, out);
    k_dist<<<g16, 256, 0, stream>>>(costP, startn, out, coreBuf);
}